// Round 11
// baseline (1172.943 us; speedup 1.0000x reference)
//
#include <hip/hip_runtime.h>

#define EDIM 512
#define NH 8
#define HD 64
#define SEQ 1024
#define BATCH 8
#define NLAYER 4
#define KSEL 256

typedef __attribute__((ext_vector_type(8))) short short8;
typedef __attribute__((ext_vector_type(4))) float f32x4;

// ---- split-bf16 helpers: f ~= hi + lo, |err| ~ 2^-17 |f| ---------------
__device__ __forceinline__ unsigned short bf16_rne(float f) {
    unsigned u = __float_as_uint(f);
    return (unsigned short)((u + 0x7FFFu + ((u >> 16) & 1u)) >> 16);
}
__device__ __forceinline__ float bf16_tof(unsigned short h) {
    return __uint_as_float(((unsigned)h) << 16);
}
__device__ __forceinline__ void split2(float f, unsigned short& hi, unsigned short& lo) {
    hi = bf16_rne(f);
    float r = f - bf16_tof(hi);
    lo = (unsigned short)(__float_as_uint(r) >> 16);
}
// truncation variant (e >= 0): same 2^-17 error class, fewer ops
__device__ __forceinline__ void split2t(float f, unsigned short& hi, unsigned short& lo) {
    hi = (unsigned short)(__float_as_uint(f) >> 16);
    float r = f - bf16_tof(hi);
    lo = (unsigned short)(__float_as_uint(r) >> 16);
}
__device__ __forceinline__ void split8(const float* xs, short8& hi, short8& lo) {
#pragma unroll
    for (int j = 0; j < 8; ++j) {
        unsigned short h, lw;
        split2(xs[j], h, lw);
        hi[j] = (short)h; lo[j] = (short)lw;
    }
}
__device__ __forceinline__ unsigned fmap(float s) {
    int fi = __float_as_int(s);
    return (unsigned)(fi ^ ((fi >> 31) | 0x80000000));
}
__device__ __forceinline__ float funmap(unsigned u) {
    int fi = (u & 0x80000000u) ? (int)(u ^ 0x80000000u) : (int)~u;
    return __int_as_float(fi);
}

// ---------------------------------------------------------------------------
// A-fragment convert (x only): grid (1, M/16), K=128.
// ---------------------------------------------------------------------------
__global__ __launch_bounds__(256) void conv_a(const float* __restrict__ A,
                                              short* __restrict__ af, int K)
{
    const int t = threadIdx.x, l = t & 63;
    const int KC = K >> 5;
    const int kc = blockIdx.x * 4 + (t >> 6);
    const int mt = blockIdx.y;
    const int m = mt * 16 + (l & 15);
    const int kb = kc * 32 + ((l >> 4) << 3);
    float4 x0 = *(const float4*)(A + (size_t)m * K + kb);
    float4 x1 = *(const float4*)(A + (size_t)m * K + kb + 4);
    float xs[8] = {x0.x, x0.y, x0.z, x0.w, x1.x, x1.y, x1.z, x1.w};
    short8 hi, lo;
    split8(xs, hi, lo);
    short* dst = af + (size_t)((mt * KC + kc) * 2) * 512 + l * 8;
    *(short8*)(dst) = hi;
    *(short8*)(dst + 512) = lo;
}

// ---------------------------------------------------------------------------
// ALL-layer weight convert: z = layer*4 + mat. grid (4,32,16).
// Wq (mat 0) pre-scaled by 0.125 (exact power of 2): q' = q/8 bit-exactly.
// ---------------------------------------------------------------------------
__global__ __launch_bounds__(256) void conv_wall(const float* __restrict__ Wq,
                                                 const float* __restrict__ Wk,
                                                 const float* __restrict__ Wv,
                                                 const float* __restrict__ Wo,
                                                 short* __restrict__ wf)
{
    const int z = blockIdx.z;
    const int layer = z >> 2, mm = z & 3;
    const float* W = (mm == 0 ? Wq : mm == 1 ? Wk : mm == 2 ? Wv : Wo)
                     + (size_t)layer * EDIM * EDIM;
    const float sc = (mm == 0) ? 0.125f : 1.0f;
    const int t = threadIdx.x, l = t & 63;
    const int kc = blockIdx.x * 4 + (t >> 6);
    const int nt = blockIdx.y;
    const int n = nt * 16 + (l & 15);
    const int kb = kc * 32 + ((l >> 4) << 3);
    float xs[8];
#pragma unroll
    for (int j = 0; j < 8; ++j) xs[j] = W[(size_t)(kb + j) * EDIM + n] * sc;
    short8 hi, lo;
    split8(xs, hi, lo);
    short* dst = wf + (size_t)z * 524288 + (size_t)((nt * 16 + kc) * 2) * 512 + l * 8;
    *(short8*)(dst) = hi;
    *(short8*)(dst + 512) = lo;
}

// single matrix variant (emb_w, K=128): grid (1, 32)
__global__ __launch_bounds__(256) void conv_w1(const float* __restrict__ W,
                                               short* __restrict__ wf, int K, int N)
{
    const int t = threadIdx.x, l = t & 63;
    const int KC = K >> 5;
    const int kc = blockIdx.x * 4 + (t >> 6);
    const int nt = blockIdx.y;
    const int n = nt * 16 + (l & 15);
    const int kb = kc * 32 + ((l >> 4) << 3);
    float xs[8];
#pragma unroll
    for (int j = 0; j < 8; ++j) xs[j] = W[(size_t)(kb + j) * N + n];
    short8 hi, lo;
    split8(xs, hi, lo);
    short* dst = wf + (size_t)((nt * KC + kc) * 2) * 512 + l * 8;
    *(short8*)(dst) = hi;
    *(short8*)(dst + 512) = lo;
}

// ---------------------------------------------------------------------------
// Split-bf16 MFMA GEMM + fused A-fragment epilogue. Cout optional.
// ---------------------------------------------------------------------------
__global__ __launch_bounds__(256, 3) void gemm_af(const short* __restrict__ af_in,
                                                  const short* __restrict__ wf,
                                                  const float* __restrict__ bias,
                                                  float* __restrict__ Cout,
                                                  short* __restrict__ af_out,
                                                  int K)
{
    __shared__ float S[128 * 68];
    const int t = threadIdx.x, l = t & 63, w = t >> 6;
    const int KC = K >> 5;
    const int mt0 = blockIdx.x * 8 + (w & 1) * 4;
    const int nt0l = (w >> 1) * 2;
    f32x4 acc[4][2] = {};

#pragma unroll 2
    for (int kc = 0; kc < KC; ++kc) {
        short8 ah[4], al[4], bh[2], bl[2];
#pragma unroll
        for (int i = 0; i < 4; ++i) {
            const short* ap = af_in + (size_t)(((mt0 + i) * KC + kc) * 2) * 512 + l * 8;
            ah[i] = *(const short8*)(ap);
            al[i] = *(const short8*)(ap + 512);
        }
#pragma unroll
        for (int j = 0; j < 2; ++j) {
            const short* bp = wf + (size_t)(((blockIdx.y * 4 + nt0l + j) * KC + kc) * 2) * 512 + l * 8;
            bh[j] = *(const short8*)(bp);
            bl[j] = *(const short8*)(bp + 512);
        }
#pragma unroll
        for (int i = 0; i < 4; ++i)
#pragma unroll
            for (int j = 0; j < 2; ++j) {
                acc[i][j] = __builtin_amdgcn_mfma_f32_16x16x32_bf16(ah[i], bh[j], acc[i][j], 0, 0, 0);
                acc[i][j] = __builtin_amdgcn_mfma_f32_16x16x32_bf16(ah[i], bl[j], acc[i][j], 0, 0, 0);
                acc[i][j] = __builtin_amdgcn_mfma_f32_16x16x32_bf16(al[i], bh[j], acc[i][j], 0, 0, 0);
            }
    }
#pragma unroll
    for (int j = 0; j < 2; ++j) {
        const int cl = (nt0l + j) * 16 + (l & 15);
        const float bv = bias[blockIdx.y * 64 + cl];
#pragma unroll
        for (int i = 0; i < 4; ++i) {
            const int rl = ((w & 1) * 4 + i) * 16 + ((l >> 4) << 2);
#pragma unroll
            for (int r = 0; r < 4; ++r) {
                const float v = acc[i][j][r] + bv;
                S[(rl + r) * 68 + cl] = v;
                if (Cout)
                    Cout[(size_t)(blockIdx.x * 128 + rl + r) * EDIM + blockIdx.y * 64 + cl] = v;
            }
        }
    }
    __syncthreads();
#pragma unroll
    for (int mi = 0; mi < 2; ++mi) {
        const int mtl = w * 2 + mi;
        const int mt = blockIdx.x * 8 + mtl;
#pragma unroll
        for (int kcl = 0; kcl < 2; ++kcl) {
            const int kc = blockIdx.y * 2 + kcl;
            const float* src = &S[(mtl * 16 + (l & 15)) * 68 + kcl * 32 + ((l >> 4) << 3)];
            float4 x0 = *(const float4*)(src);
            float4 x1 = *(const float4*)(src + 4);
            float xs[8] = {x0.x, x0.y, x0.z, x0.w, x1.x, x1.y, x1.z, x1.w};
            short8 hi, lo;
            split8(xs, hi, lo);
            short* dst = af_out + (size_t)((mt * 16 + kc) * 2) * 512 + l * 8;
            *(short8*)(dst) = hi;
            *(short8*)(dst + 512) = lo;
        }
    }
}

// ---------------------------------------------------------------------------
// Fused Q/K/V projection. grid (64, 24). y<8: Q -> qf A-fragments (Wq/bq carry
// the 1/8 scale; layout == afh); y in [8,16): K -> kf; y in [16,24): V -> vf.
// ---------------------------------------------------------------------------
__global__ __launch_bounds__(256, 3) void gemm_qkv(const short* __restrict__ af,
                                                   const short* __restrict__ wfl,
                                                   const float* __restrict__ bq,
                                                   const float* __restrict__ bk,
                                                   const float* __restrict__ bv,
                                                   short* __restrict__ qf,
                                                   short* __restrict__ kf,
                                                   short* __restrict__ vf)
{
    __shared__ float S[128 * 68];
    const int y = blockIdx.y;
    const int mat = y >> 3, e = y & 7;
    const short* wfm = wfl + (size_t)mat * 524288;
    const int t = threadIdx.x, l = t & 63, w = t >> 6;
    const int KC = EDIM >> 5;
    const int mt0 = blockIdx.x * 8 + (w & 1) * 4;
    const int nt0l = (w >> 1) * 2;
    f32x4 acc[4][2] = {};

#pragma unroll 2
    for (int kc = 0; kc < KC; ++kc) {
        short8 ah[4], al[4], bh[2], bl[2];
#pragma unroll
        for (int i = 0; i < 4; ++i) {
            const short* ap = af + (size_t)(((mt0 + i) * KC + kc) * 2) * 512 + l * 8;
            ah[i] = *(const short8*)(ap);
            al[i] = *(const short8*)(ap + 512);
        }
#pragma unroll
        for (int j = 0; j < 2; ++j) {
            const short* bp = wfm + (size_t)(((e * 4 + nt0l + j) * KC + kc) * 2) * 512 + l * 8;
            bh[j] = *(const short8*)(bp);
            bl[j] = *(const short8*)(bp + 512);
        }
#pragma unroll
        for (int i = 0; i < 4; ++i)
#pragma unroll
            for (int j = 0; j < 2; ++j) {
                acc[i][j] = __builtin_amdgcn_mfma_f32_16x16x32_bf16(ah[i], bh[j], acc[i][j], 0, 0, 0);
                acc[i][j] = __builtin_amdgcn_mfma_f32_16x16x32_bf16(ah[i], bl[j], acc[i][j], 0, 0, 0);
                acc[i][j] = __builtin_amdgcn_mfma_f32_16x16x32_bf16(al[i], bh[j], acc[i][j], 0, 0, 0);
            }
    }

    const int STR = (mat == 2) ? 66 : 68;
    const float* bias = mat == 0 ? bq : mat == 1 ? bk : bv;
    const float bsc = (mat == 0) ? 0.125f : 1.0f;
#pragma unroll
    for (int j = 0; j < 2; ++j) {
        const int cl = (nt0l + j) * 16 + (l & 15);
        const float bvx = bias[e * 64 + cl] * bsc;
#pragma unroll
        for (int i = 0; i < 4; ++i) {
            const int rl = ((w & 1) * 4 + i) * 16 + ((l >> 4) << 2);
#pragma unroll
            for (int r = 0; r < 4; ++r)
                S[(rl + r) * STR + cl] = acc[i][j][r] + bvx;
        }
    }
    __syncthreads();

    if (mat == 0) {
#pragma unroll
        for (int mi = 0; mi < 2; ++mi) {
            const int mtl = w * 2 + mi;
            const int mt = blockIdx.x * 8 + mtl;
#pragma unroll
            for (int kcl = 0; kcl < 2; ++kcl) {
                const int kc = e * 2 + kcl;
                const float* src = &S[(mtl * 16 + (l & 15)) * 68 + kcl * 32 + ((l >> 4) << 3)];
                float4 x0 = *(const float4*)(src);
                float4 x1 = *(const float4*)(src + 4);
                float xs[8] = {x0.x, x0.y, x0.z, x0.w, x1.x, x1.y, x1.z, x1.w};
                short8 hi, lo;
                split8(xs, hi, lo);
                short* dst = qf + (size_t)((mt * 16 + kc) * 2) * 512 + l * 8;
                *(short8*)(dst) = hi;
                *(short8*)(dst + 512) = lo;
            }
        }
        return;
    }

    const int b = blockIdx.x >> 3;
    const int bh2 = b * 8 + e;
    if (mat == 1) {
#pragma unroll
        for (int ki = 0; ki < 2; ++ki) {
            const int ktl = w * 2 + ki;
            const int kt = (blockIdx.x & 7) * 8 + ktl;
#pragma unroll
            for (int kc = 0; kc < 2; ++kc) {
                const float* src = &S[(ktl * 16 + (l & 15)) * 68 + kc * 32 + ((l >> 4) << 3)];
                float4 x0 = *(const float4*)(src);
                float4 x1 = *(const float4*)(src + 4);
                float xs[8] = {x0.x, x0.y, x0.z, x0.w, x1.x, x1.y, x1.z, x1.w};
                short8 hi, lo;
                split8(xs, hi, lo);
                short* dst = kf + (size_t)(((bh2 * 64 + kt) * 2 + kc) * 2) * 512 + l * 8;
                *(short8*)(dst) = hi;
                *(short8*)(dst + 512) = lo;
            }
        }
    } else {
        const int jc = (blockIdx.x & 7) * 4 + w;
#pragma unroll
        for (int n = 0; n < 4; ++n) {
            float xs[8];
#pragma unroll
            for (int j2 = 0; j2 < 8; ++j2)
                xs[j2] = S[(w * 32 + ((l >> 4) << 3) + j2) * 66 + n * 16 + (l & 15)];
            short8 hi, lo;
            split8(xs, hi, lo);
            short* dst = vf + (size_t)(((bh2 * 32 + jc) * 4 + n) * 2) * 512 + l * 8;
            *(short8*)(dst) = hi;
            *(short8*)(dst + 512) = lo;
        }
    }
}

// ---------------------------------------------------------------------------
// Fused sparse attention, PQ=32 mega-WG: 1024 threads (16 waves), 128 KB
// score LDS, 1 WG/CU (16 waves = 50% occupancy). K and V are each read from
// L2 exactly ONCE per 32 q-rows (2x reuse vs PQ=16): phase 1 computes both
// 16-row tiles per K load (12 MFMA/kt); phase 3 computes both row tiles per
// V load. 4-way partial combine + afo epilogue reuse the dead score region.
// grid (64 bh, 32 qblk).
// ---------------------------------------------------------------------------
#define SZINV (32 * 4096)

__global__ __launch_bounds__(1024, 4) void attn_mfma(const short* __restrict__ QF,
                                                     const short* __restrict__ KF,
                                                     const short* __restrict__ VF,
                                                     short* __restrict__ afo)
{
    __shared__ alignas(16) unsigned char Sb[32 * 4096 + 128];   // 131200 B

    const int bh = blockIdx.x, b = bh >> 3, hh = bh & 7;
    const int q0 = blockIdx.y * 32;
    const int t = threadIdx.x, l = t & 63, w = t >> 6;          // w in 0..15
    const int qmt = (b * SEQ + q0) >> 4;                        // m-tiles qmt, qmt+1

    // Q A-fragments for both row-tiles (scale already folded into Wq/bq)
    short8 aqh0[2], aql0[2], aqh1[2], aql1[2];
#pragma unroll
    for (int kc = 0; kc < 2; ++kc) {
        const short* qp0 = QF + (size_t)((qmt * 16 + hh * 2 + kc) * 2) * 512 + l * 8;
        const short* qp1 = QF + (size_t)(((qmt + 1) * 16 + hh * 2 + kc) * 2) * 512 + l * 8;
        aqh0[kc] = *(const short8*)(qp0);
        aql0[kc] = *(const short8*)(qp0 + 512);
        aqh1[kc] = *(const short8*)(qp1);
        aql1[kc] = *(const short8*)(qp1 + 512);
    }

    // ---- phase 1: wave w -> kt = 4w..4w+3; BOTH row tiles per K load.
    {
        const short* kfb = KF + (size_t)bh * 64 * 2048;
        const int rb4 = (l >> 4) << 2;
#pragma unroll 2
        for (int i = 0; i < 4; ++i) {
            const int kt = (w << 2) + i;
            const short* kp = kfb + (size_t)kt * 2048 + l * 8;
            short8 b00 = *(const short8*)(kp);
            short8 b01 = *(const short8*)(kp + 512);
            short8 b10 = *(const short8*)(kp + 1024);
            short8 b11 = *(const short8*)(kp + 1536);
            f32x4 a0 = {0.f, 0.f, 0.f, 0.f};
            f32x4 a1 = {0.f, 0.f, 0.f, 0.f};
            a0 = __builtin_amdgcn_mfma_f32_16x16x32_bf16(aqh0[0], b00, a0, 0, 0, 0);
            a1 = __builtin_amdgcn_mfma_f32_16x16x32_bf16(aqh1[0], b00, a1, 0, 0, 0);
            a0 = __builtin_amdgcn_mfma_f32_16x16x32_bf16(aqh0[0], b01, a0, 0, 0, 0);
            a1 = __builtin_amdgcn_mfma_f32_16x16x32_bf16(aqh1[0], b01, a1, 0, 0, 0);
            a0 = __builtin_amdgcn_mfma_f32_16x16x32_bf16(aql0[0], b00, a0, 0, 0, 0);
            a1 = __builtin_amdgcn_mfma_f32_16x16x32_bf16(aql1[0], b00, a1, 0, 0, 0);
            a0 = __builtin_amdgcn_mfma_f32_16x16x32_bf16(aqh0[1], b10, a0, 0, 0, 0);
            a1 = __builtin_amdgcn_mfma_f32_16x16x32_bf16(aqh1[1], b10, a1, 0, 0, 0);
            a0 = __builtin_amdgcn_mfma_f32_16x16x32_bf16(aqh0[1], b11, a0, 0, 0, 0);
            a1 = __builtin_amdgcn_mfma_f32_16x16x32_bf16(aqh1[1], b11, a1, 0, 0, 0);
            a0 = __builtin_amdgcn_mfma_f32_16x16x32_bf16(aql0[1], b10, a0, 0, 0, 0);
            a1 = __builtin_amdgcn_mfma_f32_16x16x32_bf16(aql1[1], b10, a1, 0, 0, 0);
            const int col = (kt << 4) + (l & 15);
            const int cg = col >> 2, wi = col & 3;
#pragma unroll
            for (int r = 0; r < 4; ++r) {
                const int row0 = rb4 + r;
                const int row1 = 16 + rb4 + r;
                *(float*)(Sb + row0 * 4096 + (((cg ^ row0) << 4) | (wi << 2))) = a0[r];
                *(float*)(Sb + row1 * 4096 + (((cg ^ row1) << 4) | (wi << 2))) = a1[r];
            }
        }
    }
    __syncthreads();

    // ---- phase 2: wave w owns rows 2w, 2w+1 (float-domain exact selection).
    {
        const int r0 = w << 1, r1 = r0 + 1;

        float s0[16], s1[16];
#pragma unroll
        for (int n = 0; n < 4; ++n) {
            float4 a = *(const float4*)(Sb + r0 * 4096 + (((l + (n << 6)) ^ r0) << 4));
            float4 c = *(const float4*)(Sb + r1 * 4096 + (((l + (n << 6)) ^ r1) << 4));
            s0[n * 4 + 0] = a.x; s0[n * 4 + 1] = a.y; s0[n * 4 + 2] = a.z; s0[n * 4 + 3] = a.w;
            s1[n * 4 + 0] = c.x; s1[n * 4 + 1] = c.y; s1[n * 4 + 2] = c.z; s1[n * 4 + 3] = c.w;
        }

        float m0 = s0[0], m1 = s1[0];
#pragma unroll
        for (int i = 1; i < 16; ++i) {
            m0 = fmaxf(m0, s0[i]);
            m1 = fmaxf(m1, s1[i]);
        }
#pragma unroll
        for (int off = 32; off > 0; off >>= 1) {
            m0 = fmaxf(m0, __shfl_xor(m0, off));
            m1 = fmaxf(m1, __shfl_xor(m1, off));
        }
        const unsigned um0 = (unsigned)__builtin_amdgcn_readfirstlane((int)fmap(m0));
        const unsigned um1 = (unsigned)__builtin_amdgcn_readfirstlane((int)fmap(m1));

        unsigned T0 = 0, T1 = 0;
        bool d0 = false, d1 = false;
        for (int bit = 31; bit >= 0; --bit) {
            const unsigned msk = 1u << bit;
            if (!d0) {
                const unsigned c0 = T0 | msk;
                if (c0 <= um0) {
                    const float fc0 = funmap(c0);
                    int n0 = 0;
#pragma unroll
                    for (int i = 0; i < 16; ++i)
                        n0 += (int)__popcll(__ballot(s0[i] >= fc0));
                    if (n0 >= KSEL) { T0 = c0; d0 = (n0 == KSEL); }
                }
            }
            if (!d1) {
                const unsigned c1 = T1 | msk;
                if (c1 <= um1) {
                    const float fc1 = funmap(c1);
                    int n1 = 0;
#pragma unroll
                    for (int i = 0; i < 16; ++i)
                        n1 += (int)__popcll(__ballot(s1[i] >= fc1));
                    if (n1 >= KSEL) { T1 = c1; d1 = (n1 == KSEL); }
                }
            }
            if (d0 & d1) break;
        }
        const float fT0 = funmap(T0), fT1 = funmap(T1);

        float Z0 = 0.f, Z1 = 0.f;
#pragma unroll
        for (int n = 0; n < 4; ++n) {
            const int gg = ((l + (n << 6)) >> 1);
            short4 H, L;
            unsigned short h, lw;
            {
                float e0 = (s0[n * 4 + 0] >= fT0) ? __expf(s0[n * 4 + 0] - m0) : 0.f;
                float e1 = (s0[n * 4 + 1] >= fT0) ? __expf(s0[n * 4 + 1] - m0) : 0.f;
                float e2 = (s0[n * 4 + 2] >= fT0) ? __expf(s0[n * 4 + 2] - m0) : 0.f;
                float e3 = (s0[n * 4 + 3] >= fT0) ? __expf(s0[n * 4 + 3] - m0) : 0.f;
                Z0 += (e0 + e1) + (e2 + e3);
                split2t(e0, h, lw); H.x = (short)h; L.x = (short)lw;
                split2t(e1, h, lw); H.y = (short)h; L.y = (short)lw;
                split2t(e2, h, lw); H.z = (short)h; L.z = (short)lw;
                split2t(e3, h, lw); H.w = (short)h; L.w = (short)lw;
                unsigned char* base0 = Sb + r0 * 4096 + (((gg ^ r0) << 4) | ((l & 1) << 3));
                *(short4*)(base0) = H;
                *(short4*)(base0 + 2048) = L;
            }
            {
                float e0 = (s1[n * 4 + 0] >= fT1) ? __expf(s1[n * 4 + 0] - m1) : 0.f;
                float e1 = (s1[n * 4 + 1] >= fT1) ? __expf(s1[n * 4 + 1] - m1) : 0.f;
                float e2 = (s1[n * 4 + 2] >= fT1) ? __expf(s1[n * 4 + 2] - m1) : 0.f;
                float e3 = (s1[n * 4 + 3] >= fT1) ? __expf(s1[n * 4 + 3] - m1) : 0.f;
                Z1 += (e0 + e1) + (e2 + e3);
                split2t(e0, h, lw); H.x = (short)h; L.x = (short)lw;
                split2t(e1, h, lw); H.y = (short)h; L.y = (short)lw;
                split2t(e2, h, lw); H.z = (short)h; L.z = (short)lw;
                split2t(e3, h, lw); H.w = (short)h; L.w = (short)lw;
                unsigned char* base1 = Sb + r1 * 4096 + (((gg ^ r1) << 4) | ((l & 1) << 3));
                *(short4*)(base1) = H;
                *(short4*)(base1 + 2048) = L;
            }
        }

#pragma unroll
        for (int off = 32; off > 0; off >>= 1) {
            Z0 += __shfl_xor(Z0, off);
            Z1 += __shfl_xor(Z1, off);
        }
        if (l == 0) {
            float* zin = (float*)(Sb + SZINV);
            zin[r0] = 1.0f / Z0;
            zin[r1] = 1.0f / Z1;
        }
    }
    __syncthreads();

    // ---- phase 3: wave w -> cht = w&3, jc quarter = w>>2; BOTH row tiles.
    f32x4 oc0 = {0.f, 0.f, 0.f, 0.f};
    f32x4 oc1 = {0.f, 0.f, 0.f, 0.f};
    const int cht = w & 3, jcq = w >> 2;
    {
        const short* vfb = VF + (size_t)bh * 32 * 4096 + (size_t)cht * 1024;
        const int m = l & 15, g3 = l >> 4;
#pragma unroll 2
        for (int i = 0; i < 8; ++i) {
            const int jc = (jcq << 3) + i;
            const short* vp = vfb + (size_t)jc * 4096 + l * 8;
            short8 vh = *(const short8*)(vp);
            short8 vl = *(const short8*)(vp + 512);
            const int gg = (jc << 2) + g3;
            const int row0 = m, row1 = 16 + m;
            const unsigned char* ab0 = Sb + row0 * 4096 + ((gg ^ row0) << 4);
            const unsigned char* ab1 = Sb + row1 * 4096 + ((gg ^ row1) << 4);
            short8 p0h = *(const short8*)(ab0);
            short8 p0l = *(const short8*)(ab0 + 2048);
            short8 p1h = *(const short8*)(ab1);
            short8 p1l = *(const short8*)(ab1 + 2048);
            oc0 = __builtin_amdgcn_mfma_f32_16x16x32_bf16(p0h, vh, oc0, 0, 0, 0);
            oc1 = __builtin_amdgcn_mfma_f32_16x16x32_bf16(p1h, vh, oc1, 0, 0, 0);
            oc0 = __builtin_amdgcn_mfma_f32_16x16x32_bf16(p0h, vl, oc0, 0, 0, 0);
            oc1 = __builtin_amdgcn_mfma_f32_16x16x32_bf16(p1h, vl, oc1, 0, 0, 0);
            oc0 = __builtin_amdgcn_mfma_f32_16x16x32_bf16(p0l, vh, oc0, 0, 0, 0);
            oc1 = __builtin_amdgcn_mfma_f32_16x16x32_bf16(p1l, vh, oc1, 0, 0, 0);
        }
    }
    __syncthreads();   // all P reads done -> score region is dead

    // 4-way partial combine in the dead score region.
    // stash layout: tile (cht,rt), slot p=jcq-1: ((cht*2+rt)*3+p)*256 floats
    {
        float* part = (float*)(Sb);
        const int ch = l & 15, rb4 = (l >> 4) << 2;
        if (jcq != 0) {
#pragma unroll
            for (int r = 0; r < 4; ++r) {
                part[(((cht * 2 + 0) * 3 + (jcq - 1)) << 8) + (rb4 + r) * 16 + ch] = oc0[r];
                part[(((cht * 2 + 1) * 3 + (jcq - 1)) << 8) + (rb4 + r) * 16 + ch] = oc1[r];
            }
        }
        __syncthreads();
        float* stage = (float*)(Sb + 24576);
        const float* zin = (const float*)(Sb + SZINV);
        if (jcq == 0) {
#pragma unroll
            for (int r = 0; r < 4; ++r) {
                float v0 = oc0[r], v1 = oc1[r];
#pragma unroll
                for (int p = 0; p < 3; ++p) {
                    v0 += part[(((cht * 2 + 0) * 3 + p) << 8) + (rb4 + r) * 16 + ch];
                    v1 += part[(((cht * 2 + 1) * 3 + p) << 8) + (rb4 + r) * 16 + ch];
                }
                stage[(rb4 + r) * 68 + cht * 16 + ch] = v0 * zin[rb4 + r];
                stage[(16 + rb4 + r) * 68 + cht * 16 + ch] = v1 * zin[16 + rb4 + r];
            }
        }
        __syncthreads();
        // afo write: waves 0-3 -> (mtl = w>>1, kcl = w&1); full-lane fragments
        if (w < 4) {
            const int mtl = w >> 1, kcl = w & 1;
            const float* src = stage + (mtl * 16 + (l & 15)) * 68 + kcl * 32 + ((l >> 4) << 3);
            float4 x0 = *(const float4*)(src);
            float4 x1 = *(const float4*)(src + 4);
            float xs[8] = {x0.x, x0.y, x0.z, x0.w, x1.x, x1.y, x1.z, x1.w};
            short8 hi, lo;
            split8(xs, hi, lo);
            const int kc = hh * 2 + kcl;
            short* dst = afo + (size_t)(((qmt + mtl) * 16 + kc) * 2) * 512 + l * 8;
            *(short8*)(dst) = hi;
            *(short8*)(dst + 512) = lo;
        }
    }
}

// ---------------------------------------------------------------------------
__global__ __launch_bounds__(256) void mean_fc(const float* __restrict__ Hf,
                                               const float* __restrict__ fcw,
                                               const float* __restrict__ fcb,
                                               float* __restrict__ out)
{
    __shared__ float hm[EDIM];
    const int b = blockIdx.x, t = threadIdx.x;
    const float* hb = Hf + (size_t)b * SEQ * EDIM;
    float s0 = 0.f, s1 = 0.f;
    for (int s = 0; s < SEQ; ++s) {
        s0 += hb[(size_t)s * EDIM + t];
        s1 += hb[(size_t)s * EDIM + t + 256];
    }
    hm[t] = s0 * (1.0f / SEQ);
    hm[t + 256] = s1 * (1.0f / SEQ);
    __syncthreads();
    if (t < 10) {
        float acc = fcb[t];
        for (int e = 0; e < EDIM; ++e) acc += hm[e] * fcw[e * 10 + t];
        out[b * 10 + t] = acc;
    }
}

// ---------------------------------------------------------------------------
extern "C" void kernel_launch(void* const* d_in, const int* in_sizes, int n_in,
                              void* d_out, int out_size, void* d_ws, size_t ws_size,
                              hipStream_t stream)
{
    const float* x     = (const float*)d_in[0];
    const float* emb_w = (const float*)d_in[1];
    const float* emb_b = (const float*)d_in[2];
    const float* Wq    = (const float*)d_in[3];
    const float* Wk    = (const float*)d_in[4];
    const float* Wv    = (const float*)d_in[5];
    const float* Wo    = (const float*)d_in[6];
    const float* bq    = (const float*)d_in[7];
    const float* bk    = (const float*)d_in[8];
    const float* bv    = (const float*)d_in[9];
    const float* bo    = (const float*)d_in[10];
    const float* fcw   = (const float*)d_in[11];
    const float* fcb   = (const float*)d_in[12];
    float* out = (float*)d_out;
    float* ws  = (float*)d_ws;

    const size_t SZ = (size_t)BATCH * SEQ * EDIM;    // 4,194,304 floats = 16 MiB
    float* h   = ws;                                  // S0: h fp32 (final layer only)
    short* qf  = (short*)(ws + SZ);                   // S1: Q frags (16 MiB exactly)
    short* afo = (short*)(ws + 2 * SZ);               // S2: attn-out frags
    short* afx = (short*)(ws + 3 * SZ);               // S3: x frags (4 MiB used)
    short* wfe = afx + 4 * 1024 * 1024;               // S3 tail: emb weight frags
    short* kf  = (short*)(ws + 4 * SZ);               // S4
    short* vf  = (short*)(ws + 5 * SZ);               // S5
    short* afh = (short*)(ws + 6 * SZ);               // S6: h frags
    short* wf  = (short*)(ws + 7 * SZ);               // S7: 16 x 524288 shorts

    const int M = BATCH * SEQ;                        // 8192
    const dim3 gG(M / 128, EDIM / 64);                // (64, 8)
    const dim3 gQKV(M / 128, 3 * EDIM / 64);          // (64, 24)
    const dim3 gA(BATCH * NH, SEQ / 32);              // (64, 32)

    conv_wall<<<dim3(4, 32, 16), 256, 0, stream>>>(Wq, Wk, Wv, Wo, wf);
    conv_w1<<<dim3(1, 32), 256, 0, stream>>>(emb_w, wfe, 128, EDIM);
    conv_a<<<dim3(1, M / 16), 256, 0, stream>>>(x, afx, 128);
    gemm_af<<<gG, 256, 0, stream>>>(afx, wfe, emb_b, nullptr, afh, 128);

    for (int l = 0; l < NLAYER; ++l) {
        const short* wfl = wf + (size_t)(4 * l) * 524288;
        gemm_qkv<<<gQKV, 256, 0, stream>>>(afh, wfl, bq + l * EDIM, bk + l * EDIM,
                                           bv + l * EDIM, qf, kf, vf);
        attn_mfma<<<gA, 1024, 0, stream>>>(qf, kf, vf, afo);
        gemm_af<<<gG, 256, 0, stream>>>(afo, wfl + 3 * 524288, bo + l * EDIM,
                                        (l == NLAYER - 1) ? h : nullptr, afh, EDIM);
    }
    mean_fc<<<8, 256, 0, stream>>>(h, fcw, fcb, out);
}

// Round 12
// 1046.777 us; speedup vs baseline: 1.1205x; 1.1205x over previous
//
#include <hip/hip_runtime.h>

#define EDIM 512
#define NH 8
#define HD 64
#define SEQ 1024
#define BATCH 8
#define NLAYER 4
#define KSEL 256

typedef __attribute__((ext_vector_type(8))) short short8;
typedef __attribute__((ext_vector_type(4))) float f32x4;

// ---- split-bf16 helpers: f ~= hi + lo, |err| ~ 2^-17 |f| ---------------
__device__ __forceinline__ unsigned short bf16_rne(float f) {
    unsigned u = __float_as_uint(f);
    return (unsigned short)((u + 0x7FFFu + ((u >> 16) & 1u)) >> 16);
}
__device__ __forceinline__ float bf16_tof(unsigned short h) {
    return __uint_as_float(((unsigned)h) << 16);
}
__device__ __forceinline__ void split2(float f, unsigned short& hi, unsigned short& lo) {
    hi = bf16_rne(f);
    float r = f - bf16_tof(hi);
    lo = (unsigned short)(__float_as_uint(r) >> 16);
}
// truncation variant (e >= 0): same 2^-17 error class, fewer ops
__device__ __forceinline__ void split2t(float f, unsigned short& hi, unsigned short& lo) {
    hi = (unsigned short)(__float_as_uint(f) >> 16);
    float r = f - bf16_tof(hi);
    lo = (unsigned short)(__float_as_uint(r) >> 16);
}
__device__ __forceinline__ void split8(const float* xs, short8& hi, short8& lo) {
#pragma unroll
    for (int j = 0; j < 8; ++j) {
        unsigned short h, lw;
        split2(xs[j], h, lw);
        hi[j] = (short)h; lo[j] = (short)lw;
    }
}
__device__ __forceinline__ unsigned fmap(float s) {
    int fi = __float_as_int(s);
    return (unsigned)(fi ^ ((fi >> 31) | 0x80000000));
}
__device__ __forceinline__ float funmap(unsigned u) {
    int fi = (u & 0x80000000u) ? (int)(u ^ 0x80000000u) : (int)~u;
    return __int_as_float(fi);
}

// ---------------------------------------------------------------------------
// A-fragment convert (x only): grid (1, M/16), K=128.
// ---------------------------------------------------------------------------
__global__ __launch_bounds__(256) void conv_a(const float* __restrict__ A,
                                              short* __restrict__ af, int K)
{
    const int t = threadIdx.x, l = t & 63;
    const int KC = K >> 5;
    const int kc = blockIdx.x * 4 + (t >> 6);
    const int mt = blockIdx.y;
    const int m = mt * 16 + (l & 15);
    const int kb = kc * 32 + ((l >> 4) << 3);
    float4 x0 = *(const float4*)(A + (size_t)m * K + kb);
    float4 x1 = *(const float4*)(A + (size_t)m * K + kb + 4);
    float xs[8] = {x0.x, x0.y, x0.z, x0.w, x1.x, x1.y, x1.z, x1.w};
    short8 hi, lo;
    split8(xs, hi, lo);
    short* dst = af + (size_t)((mt * KC + kc) * 2) * 512 + l * 8;
    *(short8*)(dst) = hi;
    *(short8*)(dst + 512) = lo;
}

// ---------------------------------------------------------------------------
// ALL-layer weight convert: z = layer*4 + mat. grid (4,32,16).
// Wq (mat 0) pre-scaled by 0.125 (exact power of 2): q' = q/8 bit-exactly.
// ---------------------------------------------------------------------------
__global__ __launch_bounds__(256) void conv_wall(const float* __restrict__ Wq,
                                                 const float* __restrict__ Wk,
                                                 const float* __restrict__ Wv,
                                                 const float* __restrict__ Wo,
                                                 short* __restrict__ wf)
{
    const int z = blockIdx.z;
    const int layer = z >> 2, mm = z & 3;
    const float* W = (mm == 0 ? Wq : mm == 1 ? Wk : mm == 2 ? Wv : Wo)
                     + (size_t)layer * EDIM * EDIM;
    const float sc = (mm == 0) ? 0.125f : 1.0f;
    const int t = threadIdx.x, l = t & 63;
    const int kc = blockIdx.x * 4 + (t >> 6);
    const int nt = blockIdx.y;
    const int n = nt * 16 + (l & 15);
    const int kb = kc * 32 + ((l >> 4) << 3);
    float xs[8];
#pragma unroll
    for (int j = 0; j < 8; ++j) xs[j] = W[(size_t)(kb + j) * EDIM + n] * sc;
    short8 hi, lo;
    split8(xs, hi, lo);
    short* dst = wf + (size_t)z * 524288 + (size_t)((nt * 16 + kc) * 2) * 512 + l * 8;
    *(short8*)(dst) = hi;
    *(short8*)(dst + 512) = lo;
}

// single matrix variant (emb_w, K=128): grid (1, 32)
__global__ __launch_bounds__(256) void conv_w1(const float* __restrict__ W,
                                               short* __restrict__ wf, int K, int N)
{
    const int t = threadIdx.x, l = t & 63;
    const int KC = K >> 5;
    const int kc = blockIdx.x * 4 + (t >> 6);
    const int nt = blockIdx.y;
    const int n = nt * 16 + (l & 15);
    const int kb = kc * 32 + ((l >> 4) << 3);
    float xs[8];
#pragma unroll
    for (int j = 0; j < 8; ++j) xs[j] = W[(size_t)(kb + j) * N + n];
    short8 hi, lo;
    split8(xs, hi, lo);
    short* dst = wf + (size_t)((nt * KC + kc) * 2) * 512 + l * 8;
    *(short8*)(dst) = hi;
    *(short8*)(dst + 512) = lo;
}

// ---------------------------------------------------------------------------
// Split-bf16 MFMA GEMM + fused A-fragment epilogue. Cout optional.
// ---------------------------------------------------------------------------
__global__ __launch_bounds__(256, 3) void gemm_af(const short* __restrict__ af_in,
                                                  const short* __restrict__ wf,
                                                  const float* __restrict__ bias,
                                                  float* __restrict__ Cout,
                                                  short* __restrict__ af_out,
                                                  int K)
{
    __shared__ float S[128 * 68];
    const int t = threadIdx.x, l = t & 63, w = t >> 6;
    const int KC = K >> 5;
    const int mt0 = blockIdx.x * 8 + (w & 1) * 4;
    const int nt0l = (w >> 1) * 2;
    f32x4 acc[4][2] = {};

#pragma unroll 2
    for (int kc = 0; kc < KC; ++kc) {
        short8 ah[4], al[4], bh[2], bl[2];
#pragma unroll
        for (int i = 0; i < 4; ++i) {
            const short* ap = af_in + (size_t)(((mt0 + i) * KC + kc) * 2) * 512 + l * 8;
            ah[i] = *(const short8*)(ap);
            al[i] = *(const short8*)(ap + 512);
        }
#pragma unroll
        for (int j = 0; j < 2; ++j) {
            const short* bp = wf + (size_t)(((blockIdx.y * 4 + nt0l + j) * KC + kc) * 2) * 512 + l * 8;
            bh[j] = *(const short8*)(bp);
            bl[j] = *(const short8*)(bp + 512);
        }
#pragma unroll
        for (int i = 0; i < 4; ++i)
#pragma unroll
            for (int j = 0; j < 2; ++j) {
                acc[i][j] = __builtin_amdgcn_mfma_f32_16x16x32_bf16(ah[i], bh[j], acc[i][j], 0, 0, 0);
                acc[i][j] = __builtin_amdgcn_mfma_f32_16x16x32_bf16(ah[i], bl[j], acc[i][j], 0, 0, 0);
                acc[i][j] = __builtin_amdgcn_mfma_f32_16x16x32_bf16(al[i], bh[j], acc[i][j], 0, 0, 0);
            }
    }
#pragma unroll
    for (int j = 0; j < 2; ++j) {
        const int cl = (nt0l + j) * 16 + (l & 15);
        const float bv = bias[blockIdx.y * 64 + cl];
#pragma unroll
        for (int i = 0; i < 4; ++i) {
            const int rl = ((w & 1) * 4 + i) * 16 + ((l >> 4) << 2);
#pragma unroll
            for (int r = 0; r < 4; ++r) {
                const float v = acc[i][j][r] + bv;
                S[(rl + r) * 68 + cl] = v;
                if (Cout)
                    Cout[(size_t)(blockIdx.x * 128 + rl + r) * EDIM + blockIdx.y * 64 + cl] = v;
            }
        }
    }
    __syncthreads();
#pragma unroll
    for (int mi = 0; mi < 2; ++mi) {
        const int mtl = w * 2 + mi;
        const int mt = blockIdx.x * 8 + mtl;
#pragma unroll
        for (int kcl = 0; kcl < 2; ++kcl) {
            const int kc = blockIdx.y * 2 + kcl;
            const float* src = &S[(mtl * 16 + (l & 15)) * 68 + kcl * 32 + ((l >> 4) << 3)];
            float4 x0 = *(const float4*)(src);
            float4 x1 = *(const float4*)(src + 4);
            float xs[8] = {x0.x, x0.y, x0.z, x0.w, x1.x, x1.y, x1.z, x1.w};
            short8 hi, lo;
            split8(xs, hi, lo);
            short* dst = af_out + (size_t)((mt * 16 + kc) * 2) * 512 + l * 8;
            *(short8*)(dst) = hi;
            *(short8*)(dst + 512) = lo;
        }
    }
}

// ---------------------------------------------------------------------------
// Fused Q/K/V projection. grid (64, 24). y<8: Q -> qf A-fragments (Wq/bq carry
// the 1/8 scale; layout == afh); y in [8,16): K -> kf; y in [16,24): V -> vf.
// ---------------------------------------------------------------------------
__global__ __launch_bounds__(256, 3) void gemm_qkv(const short* __restrict__ af,
                                                   const short* __restrict__ wfl,
                                                   const float* __restrict__ bq,
                                                   const float* __restrict__ bk,
                                                   const float* __restrict__ bv,
                                                   short* __restrict__ qf,
                                                   short* __restrict__ kf,
                                                   short* __restrict__ vf)
{
    __shared__ float S[128 * 68];
    const int y = blockIdx.y;
    const int mat = y >> 3, e = y & 7;
    const short* wfm = wfl + (size_t)mat * 524288;
    const int t = threadIdx.x, l = t & 63, w = t >> 6;
    const int KC = EDIM >> 5;
    const int mt0 = blockIdx.x * 8 + (w & 1) * 4;
    const int nt0l = (w >> 1) * 2;
    f32x4 acc[4][2] = {};

#pragma unroll 2
    for (int kc = 0; kc < KC; ++kc) {
        short8 ah[4], al[4], bh[2], bl[2];
#pragma unroll
        for (int i = 0; i < 4; ++i) {
            const short* ap = af + (size_t)(((mt0 + i) * KC + kc) * 2) * 512 + l * 8;
            ah[i] = *(const short8*)(ap);
            al[i] = *(const short8*)(ap + 512);
        }
#pragma unroll
        for (int j = 0; j < 2; ++j) {
            const short* bp = wfm + (size_t)(((e * 4 + nt0l + j) * KC + kc) * 2) * 512 + l * 8;
            bh[j] = *(const short8*)(bp);
            bl[j] = *(const short8*)(bp + 512);
        }
#pragma unroll
        for (int i = 0; i < 4; ++i)
#pragma unroll
            for (int j = 0; j < 2; ++j) {
                acc[i][j] = __builtin_amdgcn_mfma_f32_16x16x32_bf16(ah[i], bh[j], acc[i][j], 0, 0, 0);
                acc[i][j] = __builtin_amdgcn_mfma_f32_16x16x32_bf16(ah[i], bl[j], acc[i][j], 0, 0, 0);
                acc[i][j] = __builtin_amdgcn_mfma_f32_16x16x32_bf16(al[i], bh[j], acc[i][j], 0, 0, 0);
            }
    }

    const int STR = (mat == 2) ? 66 : 68;
    const float* bias = mat == 0 ? bq : mat == 1 ? bk : bv;
    const float bsc = (mat == 0) ? 0.125f : 1.0f;
#pragma unroll
    for (int j = 0; j < 2; ++j) {
        const int cl = (nt0l + j) * 16 + (l & 15);
        const float bvx = bias[e * 64 + cl] * bsc;
#pragma unroll
        for (int i = 0; i < 4; ++i) {
            const int rl = ((w & 1) * 4 + i) * 16 + ((l >> 4) << 2);
#pragma unroll
            for (int r = 0; r < 4; ++r)
                S[(rl + r) * STR + cl] = acc[i][j][r] + bvx;
        }
    }
    __syncthreads();

    if (mat == 0) {
#pragma unroll
        for (int mi = 0; mi < 2; ++mi) {
            const int mtl = w * 2 + mi;
            const int mt = blockIdx.x * 8 + mtl;
#pragma unroll
            for (int kcl = 0; kcl < 2; ++kcl) {
                const int kc = e * 2 + kcl;
                const float* src = &S[(mtl * 16 + (l & 15)) * 68 + kcl * 32 + ((l >> 4) << 3)];
                float4 x0 = *(const float4*)(src);
                float4 x1 = *(const float4*)(src + 4);
                float xs[8] = {x0.x, x0.y, x0.z, x0.w, x1.x, x1.y, x1.z, x1.w};
                short8 hi, lo;
                split8(xs, hi, lo);
                short* dst = qf + (size_t)((mt * 16 + kc) * 2) * 512 + l * 8;
                *(short8*)(dst) = hi;
                *(short8*)(dst + 512) = lo;
            }
        }
        return;
    }

    const int b = blockIdx.x >> 3;
    const int bh2 = b * 8 + e;
    if (mat == 1) {
#pragma unroll
        for (int ki = 0; ki < 2; ++ki) {
            const int ktl = w * 2 + ki;
            const int kt = (blockIdx.x & 7) * 8 + ktl;
#pragma unroll
            for (int kc = 0; kc < 2; ++kc) {
                const float* src = &S[(ktl * 16 + (l & 15)) * 68 + kc * 32 + ((l >> 4) << 3)];
                float4 x0 = *(const float4*)(src);
                float4 x1 = *(const float4*)(src + 4);
                float xs[8] = {x0.x, x0.y, x0.z, x0.w, x1.x, x1.y, x1.z, x1.w};
                short8 hi, lo;
                split8(xs, hi, lo);
                short* dst = kf + (size_t)(((bh2 * 64 + kt) * 2 + kc) * 2) * 512 + l * 8;
                *(short8*)(dst) = hi;
                *(short8*)(dst + 512) = lo;
            }
        }
    } else {
        const int jc = (blockIdx.x & 7) * 4 + w;
#pragma unroll
        for (int n = 0; n < 4; ++n) {
            float xs[8];
#pragma unroll
            for (int j2 = 0; j2 < 8; ++j2)
                xs[j2] = S[(w * 32 + ((l >> 4) << 3) + j2) * 66 + n * 16 + (l & 15)];
            short8 hi, lo;
            split8(xs, hi, lo);
            short* dst = vf + (size_t)(((bh2 * 32 + jc) * 4 + n) * 2) * 512 + l * 8;
            *(short8*)(dst) = hi;
            *(short8*)(dst + 512) = lo;
        }
    }
}

// ---------------------------------------------------------------------------
// Fused sparse attention, PQ=16 / 512-thread WG (R10 structure), with
// register double-buffer PREFETCH of global K-frag loads (phase 1) and V-frag
// loads (phase 3): iteration i+1's loads issue before iteration i's MFMAs,
// hiding ~200-cyc L2 latency behind compute. grid (64 bh, 64 qblk).
// ---------------------------------------------------------------------------
#define SPART 65536
#define SSTG  69632
#define SZINV 73984

__global__ __launch_bounds__(512, 4) void attn_mfma(const short* __restrict__ QF,
                                                    const short* __restrict__ KF,
                                                    const short* __restrict__ VF,
                                                    short* __restrict__ afo)
{
    __shared__ alignas(16) unsigned char Sb[16 * 4096 + 4096 + 4352 + 64];

    const int bh = blockIdx.x, b = bh >> 3, hh = bh & 7;
    const int q0 = blockIdx.y * 16;
    const int t = threadIdx.x, l = t & 63, w = t >> 6;
    const int qmt = (b * SEQ + q0) >> 4;

    // Q A-fragments: direct loads (scale already folded into Wq/bq)
    short8 aqh[2], aql[2];
#pragma unroll
    for (int kc = 0; kc < 2; ++kc) {
        const short* qp = QF + (size_t)((qmt * 16 + hh * 2 + kc) * 2) * 512 + l * 8;
        aqh[kc] = *(const short8*)(qp);
        aql[kc] = *(const short8*)(qp + 512);
    }

    // ---- phase 1: wave w -> key tiles 8w..8w+7; prefetched K loads.
    {
        const short* kp = KF + (size_t)bh * 64 * 2048 + (size_t)(w << 3) * 2048 + l * 8;
        const int rb = (l >> 4) << 2;
        short8 c00 = *(const short8*)(kp);
        short8 c01 = *(const short8*)(kp + 512);
        short8 c10 = *(const short8*)(kp + 1024);
        short8 c11 = *(const short8*)(kp + 1536);
#pragma unroll
        for (int i = 0; i < 8; ++i) {
            short8 n00, n01, n10, n11;
            if (i < 7) {
                const short* np = kp + (size_t)(i + 1) * 2048;
                n00 = *(const short8*)(np);
                n01 = *(const short8*)(np + 512);
                n10 = *(const short8*)(np + 1024);
                n11 = *(const short8*)(np + 1536);
            }
            f32x4 acc = {0.f, 0.f, 0.f, 0.f};
            acc = __builtin_amdgcn_mfma_f32_16x16x32_bf16(aqh[0], c00, acc, 0, 0, 0);
            acc = __builtin_amdgcn_mfma_f32_16x16x32_bf16(aqh[0], c01, acc, 0, 0, 0);
            acc = __builtin_amdgcn_mfma_f32_16x16x32_bf16(aql[0], c00, acc, 0, 0, 0);
            acc = __builtin_amdgcn_mfma_f32_16x16x32_bf16(aqh[1], c10, acc, 0, 0, 0);
            acc = __builtin_amdgcn_mfma_f32_16x16x32_bf16(aqh[1], c11, acc, 0, 0, 0);
            acc = __builtin_amdgcn_mfma_f32_16x16x32_bf16(aql[1], c10, acc, 0, 0, 0);
            const int kt = (w << 3) + i;
            const int col = (kt << 4) + (l & 15);
            const int cg = col >> 2, wi = col & 3;
#pragma unroll
            for (int r = 0; r < 4; ++r) {
                const int row = rb + r;
                *(float*)(Sb + row * 4096 + (((cg ^ row) << 4) | (wi << 2))) = acc[r];
            }
            c00 = n00; c01 = n01; c10 = n10; c11 = n11;
        }
    }
    __syncthreads();

    // ---- phase 2: wave w owns rows 2w, 2w+1 (float-domain exact selection).
    {
        const int r0 = w << 1, r1 = r0 + 1;

        float s0[16], s1[16];
#pragma unroll
        for (int n = 0; n < 4; ++n) {
            float4 a = *(const float4*)(Sb + r0 * 4096 + (((l + (n << 6)) ^ r0) << 4));
            float4 c = *(const float4*)(Sb + r1 * 4096 + (((l + (n << 6)) ^ r1) << 4));
            s0[n * 4 + 0] = a.x; s0[n * 4 + 1] = a.y; s0[n * 4 + 2] = a.z; s0[n * 4 + 3] = a.w;
            s1[n * 4 + 0] = c.x; s1[n * 4 + 1] = c.y; s1[n * 4 + 2] = c.z; s1[n * 4 + 3] = c.w;
        }

        float m0 = s0[0], m1 = s1[0];
#pragma unroll
        for (int i = 1; i < 16; ++i) {
            m0 = fmaxf(m0, s0[i]);
            m1 = fmaxf(m1, s1[i]);
        }
#pragma unroll
        for (int off = 32; off > 0; off >>= 1) {
            m0 = fmaxf(m0, __shfl_xor(m0, off));
            m1 = fmaxf(m1, __shfl_xor(m1, off));
        }
        const unsigned um0 = (unsigned)__builtin_amdgcn_readfirstlane((int)fmap(m0));
        const unsigned um1 = (unsigned)__builtin_amdgcn_readfirstlane((int)fmap(m1));

        unsigned T0 = 0, T1 = 0;
        bool d0 = false, d1 = false;
        for (int bit = 31; bit >= 0; --bit) {
            const unsigned msk = 1u << bit;
            if (!d0) {
                const unsigned c0 = T0 | msk;
                if (c0 <= um0) {
                    const float fc0 = funmap(c0);
                    int n0 = 0;
#pragma unroll
                    for (int i = 0; i < 16; ++i)
                        n0 += (int)__popcll(__ballot(s0[i] >= fc0));
                    if (n0 >= KSEL) { T0 = c0; d0 = (n0 == KSEL); }
                }
            }
            if (!d1) {
                const unsigned c1 = T1 | msk;
                if (c1 <= um1) {
                    const float fc1 = funmap(c1);
                    int n1 = 0;
#pragma unroll
                    for (int i = 0; i < 16; ++i)
                        n1 += (int)__popcll(__ballot(s1[i] >= fc1));
                    if (n1 >= KSEL) { T1 = c1; d1 = (n1 == KSEL); }
                }
            }
            if (d0 & d1) break;
        }
        const float fT0 = funmap(T0), fT1 = funmap(T1);

        float Z0 = 0.f, Z1 = 0.f;
#pragma unroll
        for (int n = 0; n < 4; ++n) {
            const int gg = ((l + (n << 6)) >> 1);
            short4 H, L;
            unsigned short h, lw;
            {
                float e0 = (s0[n * 4 + 0] >= fT0) ? __expf(s0[n * 4 + 0] - m0) : 0.f;
                float e1 = (s0[n * 4 + 1] >= fT0) ? __expf(s0[n * 4 + 1] - m0) : 0.f;
                float e2 = (s0[n * 4 + 2] >= fT0) ? __expf(s0[n * 4 + 2] - m0) : 0.f;
                float e3 = (s0[n * 4 + 3] >= fT0) ? __expf(s0[n * 4 + 3] - m0) : 0.f;
                Z0 += (e0 + e1) + (e2 + e3);
                split2t(e0, h, lw); H.x = (short)h; L.x = (short)lw;
                split2t(e1, h, lw); H.y = (short)h; L.y = (short)lw;
                split2t(e2, h, lw); H.z = (short)h; L.z = (short)lw;
                split2t(e3, h, lw); H.w = (short)h; L.w = (short)lw;
                unsigned char* base0 = Sb + r0 * 4096 + (((gg ^ r0) << 4) | ((l & 1) << 3));
                *(short4*)(base0) = H;
                *(short4*)(base0 + 2048) = L;
            }
            {
                float e0 = (s1[n * 4 + 0] >= fT1) ? __expf(s1[n * 4 + 0] - m1) : 0.f;
                float e1 = (s1[n * 4 + 1] >= fT1) ? __expf(s1[n * 4 + 1] - m1) : 0.f;
                float e2 = (s1[n * 4 + 2] >= fT1) ? __expf(s1[n * 4 + 2] - m1) : 0.f;
                float e3 = (s1[n * 4 + 3] >= fT1) ? __expf(s1[n * 4 + 3] - m1) : 0.f;
                Z1 += (e0 + e1) + (e2 + e3);
                split2t(e0, h, lw); H.x = (short)h; L.x = (short)lw;
                split2t(e1, h, lw); H.y = (short)h; L.y = (short)lw;
                split2t(e2, h, lw); H.z = (short)h; L.z = (short)lw;
                split2t(e3, h, lw); H.w = (short)h; L.w = (short)lw;
                unsigned char* base1 = Sb + r1 * 4096 + (((gg ^ r1) << 4) | ((l & 1) << 3));
                *(short4*)(base1) = H;
                *(short4*)(base1 + 2048) = L;
            }
        }

#pragma unroll
        for (int off = 32; off > 0; off >>= 1) {
            Z0 += __shfl_xor(Z0, off);
            Z1 += __shfl_xor(Z1, off);
        }
        if (l == 0) {
            float* zin = (float*)(Sb + SZINV);
            zin[r0] = 1.0f / Z0;
            zin[r1] = 1.0f / Z1;
        }
    }
    __syncthreads();

    // ---- phase 3: wave w -> ch-tile (w&3), key half (w>>2); prefetched V.
    f32x4 oacc = {0.f, 0.f, 0.f, 0.f};
    const int cht = w & 3;
    {
        const int hf = w >> 2;
        const short* vp = VF + (size_t)bh * 32 * 4096 + (size_t)cht * 1024
                        + (size_t)(hf * 16) * 4096 + l * 8;
        const int m = l & 15, g3 = l >> 4;
        short8 cvh = *(const short8*)(vp);
        short8 cvl = *(const short8*)(vp + 512);
#pragma unroll
        for (int i = 0; i < 16; ++i) {
            short8 nvh, nvl;
            if (i < 15) {
                const short* np = vp + (size_t)(i + 1) * 4096;
                nvh = *(const short8*)(np);
                nvl = *(const short8*)(np + 512);
            }
            const int jc = hf * 16 + i;
            const int gg = (jc << 2) + g3;
            const unsigned char* abase = Sb + m * 4096 + ((gg ^ m) << 4);
            short8 ph = *(const short8*)(abase);
            short8 pl = *(const short8*)(abase + 2048);
            oacc = __builtin_amdgcn_mfma_f32_16x16x32_bf16(ph, cvh, oacc, 0, 0, 0);
            oacc = __builtin_amdgcn_mfma_f32_16x16x32_bf16(ph, cvl, oacc, 0, 0, 0);
            oacc = __builtin_amdgcn_mfma_f32_16x16x32_bf16(pl, cvh, oacc, 0, 0, 0);
            cvh = nvh; cvl = nvl;
        }
    }
    // combine key-halves; scale by zinv; stage fp32
    {
        float* part = (float*)(Sb + SPART);
        const float* zin = (const float*)(Sb + SZINV);
        const int ch = l & 15, rb = (l >> 4) << 2;
        if (w >= 4) {
#pragma unroll
            for (int r = 0; r < 4; ++r)
                part[(cht * 16 + rb + r) * 16 + ch] = oacc[r];
        }
        __syncthreads();
        if (w < 4) {
            float* stage = (float*)(Sb + SSTG);
#pragma unroll
            for (int r = 0; r < 4; ++r) {
                const float v = (oacc[r] + part[(cht * 16 + rb + r) * 16 + ch]) * zin[rb + r];
                stage[(rb + r) * 68 + cht * 16 + ch] = v;
            }
        }
        __syncthreads();
    }
    // afo write: waves 0,1 (kc chunk = w); full-lane 16-row A-fragment
    if (w < 2) {
        const float* stage = (const float*)(Sb + SSTG);
        const float* src = stage + (l & 15) * 68 + w * 32 + ((l >> 4) << 3);
        float4 x0 = *(const float4*)(src);
        float4 x1 = *(const float4*)(src + 4);
        float xs[8] = {x0.x, x0.y, x0.z, x0.w, x1.x, x1.y, x1.z, x1.w};
        short8 hi, lo;
        split8(xs, hi, lo);
        const int kc = hh * 2 + w;
        short* dst = afo + (size_t)((qmt * 16 + kc) * 2) * 512 + l * 8;
        *(short8*)(dst) = hi;
        *(short8*)(dst + 512) = lo;
    }
}

// ---------------------------------------------------------------------------
__global__ __launch_bounds__(256) void mean_fc(const float* __restrict__ Hf,
                                               const float* __restrict__ fcw,
                                               const float* __restrict__ fcb,
                                               float* __restrict__ out)
{
    __shared__ float hm[EDIM];
    const int b = blockIdx.x, t = threadIdx.x;
    const float* hb = Hf + (size_t)b * SEQ * EDIM;
    float s0 = 0.f, s1 = 0.f;
    for (int s = 0; s < SEQ; ++s) {
        s0 += hb[(size_t)s * EDIM + t];
        s1 += hb[(size_t)s * EDIM + t + 256];
    }
    hm[t] = s0 * (1.0f / SEQ);
    hm[t + 256] = s1 * (1.0f / SEQ);
    __syncthreads();
    if (t < 10) {
        float acc = fcb[t];
        for (int e = 0; e < EDIM; ++e) acc += hm[e] * fcw[e * 10 + t];
        out[b * 10 + t] = acc;
    }
}

// ---------------------------------------------------------------------------
extern "C" void kernel_launch(void* const* d_in, const int* in_sizes, int n_in,
                              void* d_out, int out_size, void* d_ws, size_t ws_size,
                              hipStream_t stream)
{
    const float* x     = (const float*)d_in[0];
    const float* emb_w = (const float*)d_in[1];
    const float* emb_b = (const float*)d_in[2];
    const float* Wq    = (const float*)d_in[3];
    const float* Wk    = (const float*)d_in[4];
    const float* Wv    = (const float*)d_in[5];
    const float* Wo    = (const float*)d_in[6];
    const float* bq    = (const float*)d_in[7];
    const float* bk    = (const float*)d_in[8];
    const float* bv    = (const float*)d_in[9];
    const float* bo    = (const float*)d_in[10];
    const float* fcw   = (const float*)d_in[11];
    const float* fcb   = (const float*)d_in[12];
    float* out = (float*)d_out;
    float* ws  = (float*)d_ws;

    const size_t SZ = (size_t)BATCH * SEQ * EDIM;    // 4,194,304 floats = 16 MiB
    float* h   = ws;                                  // S0: h fp32 (final layer only)
    short* qf  = (short*)(ws + SZ);                   // S1: Q frags (16 MiB exactly)
    short* afo = (short*)(ws + 2 * SZ);               // S2: attn-out frags
    short* afx = (short*)(ws + 3 * SZ);               // S3: x frags (4 MiB used)
    short* wfe = afx + 4 * 1024 * 1024;               // S3 tail: emb weight frags
    short* kf  = (short*)(ws + 4 * SZ);               // S4
    short* vf  = (short*)(ws + 5 * SZ);               // S5
    short* afh = (short*)(ws + 6 * SZ);               // S6: h frags
    short* wf  = (short*)(ws + 7 * SZ);               // S7: 16 x 524288 shorts

    const int M = BATCH * SEQ;                        // 8192
    const dim3 gG(M / 128, EDIM / 64);                // (64, 8)
    const dim3 gQKV(M / 128, 3 * EDIM / 64);          // (64, 24)
    const dim3 gA(BATCH * NH, SEQ / 16);              // (64, 64)

    conv_wall<<<dim3(4, 32, 16), 256, 0, stream>>>(Wq, Wk, Wv, Wo, wf);
    conv_w1<<<dim3(1, 32), 256, 0, stream>>>(emb_w, wfe, 128, EDIM);
    conv_a<<<dim3(1, M / 16), 256, 0, stream>>>(x, afx, 128);
    gemm_af<<<gG, 256, 0, stream>>>(afx, wfe, emb_b, nullptr, afh, 128);

    for (int l = 0; l < NLAYER; ++l) {
        const short* wfl = wf + (size_t)(4 * l) * 524288;
        gemm_qkv<<<gQKV, 256, 0, stream>>>(afh, wfl, bq + l * EDIM, bk + l * EDIM,
                                           bv + l * EDIM, qf, kf, vf);
        attn_mfma<<<gA, 512, 0, stream>>>(qf, kf, vf, afo);
        gemm_af<<<gG, 256, 0, stream>>>(afo, wfl + 3 * 524288, bo + l * EDIM,
                                        (l == NLAYER - 1) ? h : nullptr, afh, EDIM);
    }
    mean_fc<<<8, 256, 0, stream>>>(h, fcw, fcb, out);
}

// Round 13
// 1012.628 us; speedup vs baseline: 1.1583x; 1.0337x over previous
//
#include <hip/hip_runtime.h>

#define EDIM 512
#define NH 8
#define HD 64
#define SEQ 1024
#define BATCH 8
#define NLAYER 4
#define KSEL 256

typedef __attribute__((ext_vector_type(8))) short short8;
typedef __attribute__((ext_vector_type(4))) float f32x4;

// ---- split-bf16 helpers: f ~= hi + lo, |err| ~ 2^-17 |f| ---------------
__device__ __forceinline__ unsigned short bf16_rne(float f) {
    unsigned u = __float_as_uint(f);
    return (unsigned short)((u + 0x7FFFu + ((u >> 16) & 1u)) >> 16);
}
__device__ __forceinline__ float bf16_tof(unsigned short h) {
    return __uint_as_float(((unsigned)h) << 16);
}
__device__ __forceinline__ void split2(float f, unsigned short& hi, unsigned short& lo) {
    hi = bf16_rne(f);
    float r = f - bf16_tof(hi);
    lo = (unsigned short)(__float_as_uint(r) >> 16);
}
// truncation variant (e >= 0): same 2^-17 error class, fewer ops
__device__ __forceinline__ void split2t(float f, unsigned short& hi, unsigned short& lo) {
    hi = (unsigned short)(__float_as_uint(f) >> 16);
    float r = f - bf16_tof(hi);
    lo = (unsigned short)(__float_as_uint(r) >> 16);
}
__device__ __forceinline__ void split8(const float* xs, short8& hi, short8& lo) {
#pragma unroll
    for (int j = 0; j < 8; ++j) {
        unsigned short h, lw;
        split2(xs[j], h, lw);
        hi[j] = (short)h; lo[j] = (short)lw;
    }
}
__device__ __forceinline__ unsigned fmap(float s) {
    int fi = __float_as_int(s);
    return (unsigned)(fi ^ ((fi >> 31) | 0x80000000));
}
__device__ __forceinline__ float funmap(unsigned u) {
    int fi = (u & 0x80000000u) ? (int)(u ^ 0x80000000u) : (int)~u;
    return __int_as_float(fi);
}

// ---------------------------------------------------------------------------
// A-fragment convert (x only): grid (1, M/16), K=128.
// ---------------------------------------------------------------------------
__global__ __launch_bounds__(256) void conv_a(const float* __restrict__ A,
                                              short* __restrict__ af, int K)
{
    const int t = threadIdx.x, l = t & 63;
    const int KC = K >> 5;
    const int kc = blockIdx.x * 4 + (t >> 6);
    const int mt = blockIdx.y;
    const int m = mt * 16 + (l & 15);
    const int kb = kc * 32 + ((l >> 4) << 3);
    float4 x0 = *(const float4*)(A + (size_t)m * K + kb);
    float4 x1 = *(const float4*)(A + (size_t)m * K + kb + 4);
    float xs[8] = {x0.x, x0.y, x0.z, x0.w, x1.x, x1.y, x1.z, x1.w};
    short8 hi, lo;
    split8(xs, hi, lo);
    short* dst = af + (size_t)((mt * KC + kc) * 2) * 512 + l * 8;
    *(short8*)(dst) = hi;
    *(short8*)(dst + 512) = lo;
}

// ---------------------------------------------------------------------------
// ALL-layer weight convert: z = layer*4 + mat. grid (4,32,16).
// Wq (mat 0) pre-scaled by 0.125 (exact power of 2): q' = q/8 bit-exactly.
// ---------------------------------------------------------------------------
__global__ __launch_bounds__(256) void conv_wall(const float* __restrict__ Wq,
                                                 const float* __restrict__ Wk,
                                                 const float* __restrict__ Wv,
                                                 const float* __restrict__ Wo,
                                                 short* __restrict__ wf)
{
    const int z = blockIdx.z;
    const int layer = z >> 2, mm = z & 3;
    const float* W = (mm == 0 ? Wq : mm == 1 ? Wk : mm == 2 ? Wv : Wo)
                     + (size_t)layer * EDIM * EDIM;
    const float sc = (mm == 0) ? 0.125f : 1.0f;
    const int t = threadIdx.x, l = t & 63;
    const int kc = blockIdx.x * 4 + (t >> 6);
    const int nt = blockIdx.y;
    const int n = nt * 16 + (l & 15);
    const int kb = kc * 32 + ((l >> 4) << 3);
    float xs[8];
#pragma unroll
    for (int j = 0; j < 8; ++j) xs[j] = W[(size_t)(kb + j) * EDIM + n] * sc;
    short8 hi, lo;
    split8(xs, hi, lo);
    short* dst = wf + (size_t)z * 524288 + (size_t)((nt * 16 + kc) * 2) * 512 + l * 8;
    *(short8*)(dst) = hi;
    *(short8*)(dst + 512) = lo;
}

// single matrix variant (emb_w, K=128): grid (1, 32)
__global__ __launch_bounds__(256) void conv_w1(const float* __restrict__ W,
                                               short* __restrict__ wf, int K, int N)
{
    const int t = threadIdx.x, l = t & 63;
    const int KC = K >> 5;
    const int kc = blockIdx.x * 4 + (t >> 6);
    const int nt = blockIdx.y;
    const int n = nt * 16 + (l & 15);
    const int kb = kc * 32 + ((l >> 4) << 3);
    float xs[8];
#pragma unroll
    for (int j = 0; j < 8; ++j) xs[j] = W[(size_t)(kb + j) * N + n];
    short8 hi, lo;
    split8(xs, hi, lo);
    short* dst = wf + (size_t)((nt * KC + kc) * 2) * 512 + l * 8;
    *(short8*)(dst) = hi;
    *(short8*)(dst + 512) = lo;
}

// ---------------------------------------------------------------------------
// Split-bf16 MFMA GEMM + fused A-fragment epilogue. Cout optional.
// (256,4): 4 WG/CU to hide the L2 latency of the 12-load K-loop iteration.
// ---------------------------------------------------------------------------
__global__ __launch_bounds__(256, 4) void gemm_af(const short* __restrict__ af_in,
                                                  const short* __restrict__ wf,
                                                  const float* __restrict__ bias,
                                                  float* __restrict__ Cout,
                                                  short* __restrict__ af_out,
                                                  int K)
{
    __shared__ float S[128 * 68];
    const int t = threadIdx.x, l = t & 63, w = t >> 6;
    const int KC = K >> 5;
    const int mt0 = blockIdx.x * 8 + (w & 1) * 4;
    const int nt0l = (w >> 1) * 2;
    f32x4 acc[4][2] = {};

#pragma unroll 2
    for (int kc = 0; kc < KC; ++kc) {
        short8 ah[4], al[4], bh[2], bl[2];
#pragma unroll
        for (int i = 0; i < 4; ++i) {
            const short* ap = af_in + (size_t)(((mt0 + i) * KC + kc) * 2) * 512 + l * 8;
            ah[i] = *(const short8*)(ap);
            al[i] = *(const short8*)(ap + 512);
        }
#pragma unroll
        for (int j = 0; j < 2; ++j) {
            const short* bp = wf + (size_t)(((blockIdx.y * 4 + nt0l + j) * KC + kc) * 2) * 512 + l * 8;
            bh[j] = *(const short8*)(bp);
            bl[j] = *(const short8*)(bp + 512);
        }
#pragma unroll
        for (int i = 0; i < 4; ++i)
#pragma unroll
            for (int j = 0; j < 2; ++j) {
                acc[i][j] = __builtin_amdgcn_mfma_f32_16x16x32_bf16(ah[i], bh[j], acc[i][j], 0, 0, 0);
                acc[i][j] = __builtin_amdgcn_mfma_f32_16x16x32_bf16(ah[i], bl[j], acc[i][j], 0, 0, 0);
                acc[i][j] = __builtin_amdgcn_mfma_f32_16x16x32_bf16(al[i], bh[j], acc[i][j], 0, 0, 0);
            }
    }
#pragma unroll
    for (int j = 0; j < 2; ++j) {
        const int cl = (nt0l + j) * 16 + (l & 15);
        const float bv = bias[blockIdx.y * 64 + cl];
#pragma unroll
        for (int i = 0; i < 4; ++i) {
            const int rl = ((w & 1) * 4 + i) * 16 + ((l >> 4) << 2);
#pragma unroll
            for (int r = 0; r < 4; ++r) {
                const float v = acc[i][j][r] + bv;
                S[(rl + r) * 68 + cl] = v;
                if (Cout)
                    Cout[(size_t)(blockIdx.x * 128 + rl + r) * EDIM + blockIdx.y * 64 + cl] = v;
            }
        }
    }
    __syncthreads();
#pragma unroll
    for (int mi = 0; mi < 2; ++mi) {
        const int mtl = w * 2 + mi;
        const int mt = blockIdx.x * 8 + mtl;
#pragma unroll
        for (int kcl = 0; kcl < 2; ++kcl) {
            const int kc = blockIdx.y * 2 + kcl;
            const float* src = &S[(mtl * 16 + (l & 15)) * 68 + kcl * 32 + ((l >> 4) << 3)];
            float4 x0 = *(const float4*)(src);
            float4 x1 = *(const float4*)(src + 4);
            float xs[8] = {x0.x, x0.y, x0.z, x0.w, x1.x, x1.y, x1.z, x1.w};
            short8 hi, lo;
            split8(xs, hi, lo);
            short* dst = af_out + (size_t)((mt * 16 + kc) * 2) * 512 + l * 8;
            *(short8*)(dst) = hi;
            *(short8*)(dst + 512) = lo;
        }
    }
}

// ---------------------------------------------------------------------------
// Fused Q/K/V projection. grid (64, 24). y<8: Q -> qf A-fragments (Wq/bq carry
// the 1/8 scale; layout == afh); y in [8,16): K -> kf; y in [16,24): V -> vf.
// (256,4): 4 WG/CU.
// ---------------------------------------------------------------------------
__global__ __launch_bounds__(256, 4) void gemm_qkv(const short* __restrict__ af,
                                                   const short* __restrict__ wfl,
                                                   const float* __restrict__ bq,
                                                   const float* __restrict__ bk,
                                                   const float* __restrict__ bv,
                                                   short* __restrict__ qf,
                                                   short* __restrict__ kf,
                                                   short* __restrict__ vf)
{
    __shared__ float S[128 * 68];
    const int y = blockIdx.y;
    const int mat = y >> 3, e = y & 7;
    const short* wfm = wfl + (size_t)mat * 524288;
    const int t = threadIdx.x, l = t & 63, w = t >> 6;
    const int KC = EDIM >> 5;
    const int mt0 = blockIdx.x * 8 + (w & 1) * 4;
    const int nt0l = (w >> 1) * 2;
    f32x4 acc[4][2] = {};

#pragma unroll 2
    for (int kc = 0; kc < KC; ++kc) {
        short8 ah[4], al[4], bh[2], bl[2];
#pragma unroll
        for (int i = 0; i < 4; ++i) {
            const short* ap = af + (size_t)(((mt0 + i) * KC + kc) * 2) * 512 + l * 8;
            ah[i] = *(const short8*)(ap);
            al[i] = *(const short8*)(ap + 512);
        }
#pragma unroll
        for (int j = 0; j < 2; ++j) {
            const short* bp = wfm + (size_t)(((e * 4 + nt0l + j) * KC + kc) * 2) * 512 + l * 8;
            bh[j] = *(const short8*)(bp);
            bl[j] = *(const short8*)(bp + 512);
        }
#pragma unroll
        for (int i = 0; i < 4; ++i)
#pragma unroll
            for (int j = 0; j < 2; ++j) {
                acc[i][j] = __builtin_amdgcn_mfma_f32_16x16x32_bf16(ah[i], bh[j], acc[i][j], 0, 0, 0);
                acc[i][j] = __builtin_amdgcn_mfma_f32_16x16x32_bf16(ah[i], bl[j], acc[i][j], 0, 0, 0);
                acc[i][j] = __builtin_amdgcn_mfma_f32_16x16x32_bf16(al[i], bh[j], acc[i][j], 0, 0, 0);
            }
    }

    const int STR = (mat == 2) ? 66 : 68;
    const float* bias = mat == 0 ? bq : mat == 1 ? bk : bv;
    const float bsc = (mat == 0) ? 0.125f : 1.0f;
#pragma unroll
    for (int j = 0; j < 2; ++j) {
        const int cl = (nt0l + j) * 16 + (l & 15);
        const float bvx = bias[e * 64 + cl] * bsc;
#pragma unroll
        for (int i = 0; i < 4; ++i) {
            const int rl = ((w & 1) * 4 + i) * 16 + ((l >> 4) << 2);
#pragma unroll
            for (int r = 0; r < 4; ++r)
                S[(rl + r) * STR + cl] = acc[i][j][r] + bvx;
        }
    }
    __syncthreads();

    if (mat == 0) {
#pragma unroll
        for (int mi = 0; mi < 2; ++mi) {
            const int mtl = w * 2 + mi;
            const int mt = blockIdx.x * 8 + mtl;
#pragma unroll
            for (int kcl = 0; kcl < 2; ++kcl) {
                const int kc = e * 2 + kcl;
                const float* src = &S[(mtl * 16 + (l & 15)) * 68 + kcl * 32 + ((l >> 4) << 3)];
                float4 x0 = *(const float4*)(src);
                float4 x1 = *(const float4*)(src + 4);
                float xs[8] = {x0.x, x0.y, x0.z, x0.w, x1.x, x1.y, x1.z, x1.w};
                short8 hi, lo;
                split8(xs, hi, lo);
                short* dst = qf + (size_t)((mt * 16 + kc) * 2) * 512 + l * 8;
                *(short8*)(dst) = hi;
                *(short8*)(dst + 512) = lo;
            }
        }
        return;
    }

    const int b = blockIdx.x >> 3;
    const int bh2 = b * 8 + e;
    if (mat == 1) {
#pragma unroll
        for (int ki = 0; ki < 2; ++ki) {
            const int ktl = w * 2 + ki;
            const int kt = (blockIdx.x & 7) * 8 + ktl;
#pragma unroll
            for (int kc = 0; kc < 2; ++kc) {
                const float* src = &S[(ktl * 16 + (l & 15)) * 68 + kc * 32 + ((l >> 4) << 3)];
                float4 x0 = *(const float4*)(src);
                float4 x1 = *(const float4*)(src + 4);
                float xs[8] = {x0.x, x0.y, x0.z, x0.w, x1.x, x1.y, x1.z, x1.w};
                short8 hi, lo;
                split8(xs, hi, lo);
                short* dst = kf + (size_t)(((bh2 * 64 + kt) * 2 + kc) * 2) * 512 + l * 8;
                *(short8*)(dst) = hi;
                *(short8*)(dst + 512) = lo;
            }
        }
    } else {
        const int jc = (blockIdx.x & 7) * 4 + w;
#pragma unroll
        for (int n = 0; n < 4; ++n) {
            float xs[8];
#pragma unroll
            for (int j2 = 0; j2 < 8; ++j2)
                xs[j2] = S[(w * 32 + ((l >> 4) << 3) + j2) * 66 + n * 16 + (l & 15)];
            short8 hi, lo;
            split8(xs, hi, lo);
            short* dst = vf + (size_t)(((bh2 * 32 + jc) * 4 + n) * 2) * 512 + l * 8;
            *(short8*)(dst) = hi;
            *(short8*)(dst + 512) = lo;
        }
    }
}

// ---------------------------------------------------------------------------
// Fused sparse attention, PQ=16 / 512-thread WG. Phase-3's first V pair is
// prefetched BEFORE the phase-2 search (independent loads cross the barrier
// in registers). exp uses raw scores (softmax shift-invariance; |s| < 1 so
// no overflow; row max still computed for the search's max-skip bound).
// grid (64 bh, 64 qblk).
// ---------------------------------------------------------------------------
#define SPART 65536
#define SSTG  69632
#define SZINV 73984

__global__ __launch_bounds__(512, 4) void attn_mfma(const short* __restrict__ QF,
                                                    const short* __restrict__ KF,
                                                    const short* __restrict__ VF,
                                                    short* __restrict__ afo)
{
    __shared__ alignas(16) unsigned char Sb[16 * 4096 + 4096 + 4352 + 64];

    const int bh = blockIdx.x, b = bh >> 3, hh = bh & 7;
    const int q0 = blockIdx.y * 16;
    const int t = threadIdx.x, l = t & 63, w = t >> 6;
    const int qmt = (b * SEQ + q0) >> 4;

    // Q A-fragments: direct loads (scale already folded into Wq/bq)
    short8 aqh[2], aql[2];
#pragma unroll
    for (int kc = 0; kc < 2; ++kc) {
        const short* qp = QF + (size_t)((qmt * 16 + hh * 2 + kc) * 2) * 512 + l * 8;
        aqh[kc] = *(const short8*)(qp);
        aql[kc] = *(const short8*)(qp + 512);
    }

    // ---- phase 1: wave w -> key tiles 8w..8w+7; prefetched K loads.
    {
        const short* kp = KF + (size_t)bh * 64 * 2048 + (size_t)(w << 3) * 2048 + l * 8;
        const int rb = (l >> 4) << 2;
        short8 c00 = *(const short8*)(kp);
        short8 c01 = *(const short8*)(kp + 512);
        short8 c10 = *(const short8*)(kp + 1024);
        short8 c11 = *(const short8*)(kp + 1536);
#pragma unroll
        for (int i = 0; i < 8; ++i) {
            short8 n00, n01, n10, n11;
            if (i < 7) {
                const short* np = kp + (size_t)(i + 1) * 2048;
                n00 = *(const short8*)(np);
                n01 = *(const short8*)(np + 512);
                n10 = *(const short8*)(np + 1024);
                n11 = *(const short8*)(np + 1536);
            }
            f32x4 acc = {0.f, 0.f, 0.f, 0.f};
            acc = __builtin_amdgcn_mfma_f32_16x16x32_bf16(aqh[0], c00, acc, 0, 0, 0);
            acc = __builtin_amdgcn_mfma_f32_16x16x32_bf16(aqh[0], c01, acc, 0, 0, 0);
            acc = __builtin_amdgcn_mfma_f32_16x16x32_bf16(aql[0], c00, acc, 0, 0, 0);
            acc = __builtin_amdgcn_mfma_f32_16x16x32_bf16(aqh[1], c10, acc, 0, 0, 0);
            acc = __builtin_amdgcn_mfma_f32_16x16x32_bf16(aqh[1], c11, acc, 0, 0, 0);
            acc = __builtin_amdgcn_mfma_f32_16x16x32_bf16(aql[1], c10, acc, 0, 0, 0);
            const int kt = (w << 3) + i;
            const int col = (kt << 4) + (l & 15);
            const int cg = col >> 2, wi = col & 3;
#pragma unroll
            for (int r = 0; r < 4; ++r) {
                const int row = rb + r;
                *(float*)(Sb + row * 4096 + (((cg ^ row) << 4) | (wi << 2))) = acc[r];
            }
            c00 = n00; c01 = n01; c10 = n10; c11 = n11;
        }
    }
    __syncthreads();

    // phase-3 V base + first-pair prefetch (independent of phase 2)
    const int cht = w & 3;
    const short* vp = VF + (size_t)bh * 32 * 4096 + (size_t)cht * 1024
                    + (size_t)((w >> 2) * 16) * 4096 + l * 8;
    short8 cvh = *(const short8*)(vp);
    short8 cvl = *(const short8*)(vp + 512);

    // ---- phase 2: wave w owns rows 2w, 2w+1 (float-domain exact selection).
    {
        const int r0 = w << 1, r1 = r0 + 1;

        float s0[16], s1[16];
#pragma unroll
        for (int n = 0; n < 4; ++n) {
            float4 a = *(const float4*)(Sb + r0 * 4096 + (((l + (n << 6)) ^ r0) << 4));
            float4 c = *(const float4*)(Sb + r1 * 4096 + (((l + (n << 6)) ^ r1) << 4));
            s0[n * 4 + 0] = a.x; s0[n * 4 + 1] = a.y; s0[n * 4 + 2] = a.z; s0[n * 4 + 3] = a.w;
            s1[n * 4 + 0] = c.x; s1[n * 4 + 1] = c.y; s1[n * 4 + 2] = c.z; s1[n * 4 + 3] = c.w;
        }

        float m0 = s0[0], m1 = s1[0];
#pragma unroll
        for (int i = 1; i < 16; ++i) {
            m0 = fmaxf(m0, s0[i]);
            m1 = fmaxf(m1, s1[i]);
        }
#pragma unroll
        for (int off = 32; off > 0; off >>= 1) {
            m0 = fmaxf(m0, __shfl_xor(m0, off));
            m1 = fmaxf(m1, __shfl_xor(m1, off));
        }
        const unsigned um0 = (unsigned)__builtin_amdgcn_readfirstlane((int)fmap(m0));
        const unsigned um1 = (unsigned)__builtin_amdgcn_readfirstlane((int)fmap(m1));

        unsigned T0 = 0, T1 = 0;
        bool d0 = false, d1 = false;
        for (int bit = 31; bit >= 0; --bit) {
            const unsigned msk = 1u << bit;
            if (!d0) {
                const unsigned c0 = T0 | msk;
                if (c0 <= um0) {
                    const float fc0 = funmap(c0);
                    int n0 = 0;
#pragma unroll
                    for (int i = 0; i < 16; ++i)
                        n0 += (int)__popcll(__ballot(s0[i] >= fc0));
                    if (n0 >= KSEL) { T0 = c0; d0 = (n0 == KSEL); }
                }
            }
            if (!d1) {
                const unsigned c1 = T1 | msk;
                if (c1 <= um1) {
                    const float fc1 = funmap(c1);
                    int n1 = 0;
#pragma unroll
                    for (int i = 0; i < 16; ++i)
                        n1 += (int)__popcll(__ballot(s1[i] >= fc1));
                    if (n1 >= KSEL) { T1 = c1; d1 = (n1 == KSEL); }
                }
            }
            if (d0 & d1) break;
        }
        const float fT0 = funmap(T0), fT1 = funmap(T1);

        // e = exp(s) raw (shift-invariant; |s| < 1); trunc split; Z accum
        float Z0 = 0.f, Z1 = 0.f;
#pragma unroll
        for (int n = 0; n < 4; ++n) {
            const int gg = ((l + (n << 6)) >> 1);
            short4 H, L;
            unsigned short h, lw;
            {
                float e0 = (s0[n * 4 + 0] >= fT0) ? __expf(s0[n * 4 + 0]) : 0.f;
                float e1 = (s0[n * 4 + 1] >= fT0) ? __expf(s0[n * 4 + 1]) : 0.f;
                float e2 = (s0[n * 4 + 2] >= fT0) ? __expf(s0[n * 4 + 2]) : 0.f;
                float e3 = (s0[n * 4 + 3] >= fT0) ? __expf(s0[n * 4 + 3]) : 0.f;
                Z0 += (e0 + e1) + (e2 + e3);
                split2t(e0, h, lw); H.x = (short)h; L.x = (short)lw;
                split2t(e1, h, lw); H.y = (short)h; L.y = (short)lw;
                split2t(e2, h, lw); H.z = (short)h; L.z = (short)lw;
                split2t(e3, h, lw); H.w = (short)h; L.w = (short)lw;
                unsigned char* base0 = Sb + r0 * 4096 + (((gg ^ r0) << 4) | ((l & 1) << 3));
                *(short4*)(base0) = H;
                *(short4*)(base0 + 2048) = L;
            }
            {
                float e0 = (s1[n * 4 + 0] >= fT1) ? __expf(s1[n * 4 + 0]) : 0.f;
                float e1 = (s1[n * 4 + 1] >= fT1) ? __expf(s1[n * 4 + 1]) : 0.f;
                float e2 = (s1[n * 4 + 2] >= fT1) ? __expf(s1[n * 4 + 2]) : 0.f;
                float e3 = (s1[n * 4 + 3] >= fT1) ? __expf(s1[n * 4 + 3]) : 0.f;
                Z1 += (e0 + e1) + (e2 + e3);
                split2t(e0, h, lw); H.x = (short)h; L.x = (short)lw;
                split2t(e1, h, lw); H.y = (short)h; L.y = (short)lw;
                split2t(e2, h, lw); H.z = (short)h; L.z = (short)lw;
                split2t(e3, h, lw); H.w = (short)h; L.w = (short)lw;
                unsigned char* base1 = Sb + r1 * 4096 + (((gg ^ r1) << 4) | ((l & 1) << 3));
                *(short4*)(base1) = H;
                *(short4*)(base1 + 2048) = L;
            }
        }

#pragma unroll
        for (int off = 32; off > 0; off >>= 1) {
            Z0 += __shfl_xor(Z0, off);
            Z1 += __shfl_xor(Z1, off);
        }
        if (l == 0) {
            float* zin = (float*)(Sb + SZINV);
            zin[r0] = 1.0f / Z0;
            zin[r1] = 1.0f / Z1;
        }
    }
    __syncthreads();

    // ---- phase 3: wave w -> ch-tile (w&3), key half (w>>2); prefetched V.
    f32x4 oacc = {0.f, 0.f, 0.f, 0.f};
    {
        const int hf = w >> 2;
        const int m = l & 15, g3 = l >> 4;
#pragma unroll
        for (int i = 0; i < 16; ++i) {
            short8 nvh, nvl;
            if (i < 15) {
                const short* np = vp + (size_t)(i + 1) * 4096;
                nvh = *(const short8*)(np);
                nvl = *(const short8*)(np + 512);
            }
            const int jc = hf * 16 + i;
            const int gg = (jc << 2) + g3;
            const unsigned char* abase = Sb + m * 4096 + ((gg ^ m) << 4);
            short8 ph = *(const short8*)(abase);
            short8 pl = *(const short8*)(abase + 2048);
            oacc = __builtin_amdgcn_mfma_f32_16x16x32_bf16(ph, cvh, oacc, 0, 0, 0);
            oacc = __builtin_amdgcn_mfma_f32_16x16x32_bf16(ph, cvl, oacc, 0, 0, 0);
            oacc = __builtin_amdgcn_mfma_f32_16x16x32_bf16(pl, cvh, oacc, 0, 0, 0);
            cvh = nvh; cvl = nvl;
        }
    }
    // combine key-halves; scale by zinv; stage fp32
    {
        float* part = (float*)(Sb + SPART);
        const float* zin = (const float*)(Sb + SZINV);
        const int ch = l & 15, rb = (l >> 4) << 2;
        if (w >= 4) {
#pragma unroll
            for (int r = 0; r < 4; ++r)
                part[(cht * 16 + rb + r) * 16 + ch] = oacc[r];
        }
        __syncthreads();
        if (w < 4) {
            float* stage = (float*)(Sb + SSTG);
#pragma unroll
            for (int r = 0; r < 4; ++r) {
                const float v = (oacc[r] + part[(cht * 16 + rb + r) * 16 + ch]) * zin[rb + r];
                stage[(rb + r) * 68 + cht * 16 + ch] = v;
            }
        }
        __syncthreads();
    }
    // afo write: waves 0,1 (kc chunk = w); full-lane 16-row A-fragment
    if (w < 2) {
        const float* stage = (const float*)(Sb + SSTG);
        const float* src = stage + (l & 15) * 68 + w * 32 + ((l >> 4) << 3);
        float4 x0 = *(const float4*)(src);
        float4 x1 = *(const float4*)(src + 4);
        float xs[8] = {x0.x, x0.y, x0.z, x0.w, x1.x, x1.y, x1.z, x1.w};
        short8 hi, lo;
        split8(xs, hi, lo);
        const int kc = hh * 2 + w;
        short* dst = afo + (size_t)((qmt * 16 + kc) * 2) * 512 + l * 8;
        *(short8*)(dst) = hi;
        *(short8*)(dst + 512) = lo;
    }
}

// ---------------------------------------------------------------------------
__global__ __launch_bounds__(256) void mean_fc(const float* __restrict__ Hf,
                                               const float* __restrict__ fcw,
                                               const float* __restrict__ fcb,
                                               float* __restrict__ out)
{
    __shared__ float hm[EDIM];
    const int b = blockIdx.x, t = threadIdx.x;
    const float* hb = Hf + (size_t)b * SEQ * EDIM;
    float s0 = 0.f, s1 = 0.f;
    for (int s = 0; s < SEQ; ++s) {
        s0 += hb[(size_t)s * EDIM + t];
        s1 += hb[(size_t)s * EDIM + t + 256];
    }
    hm[t] = s0 * (1.0f / SEQ);
    hm[t + 256] = s1 * (1.0f / SEQ);
    __syncthreads();
    if (t < 10) {
        float acc = fcb[t];
        for (int e = 0; e < EDIM; ++e) acc += hm[e] * fcw[e * 10 + t];
        out[b * 10 + t] = acc;
    }
}

// ---------------------------------------------------------------------------
extern "C" void kernel_launch(void* const* d_in, const int* in_sizes, int n_in,
                              void* d_out, int out_size, void* d_ws, size_t ws_size,
                              hipStream_t stream)
{
    const float* x     = (const float*)d_in[0];
    const float* emb_w = (const float*)d_in[1];
    const float* emb_b = (const float*)d_in[2];
    const float* Wq    = (const float*)d_in[3];
    const float* Wk    = (const float*)d_in[4];
    const float* Wv    = (const float*)d_in[5];
    const float* Wo    = (const float*)d_in[6];
    const float* bq    = (const float*)d_in[7];
    const float* bk    = (const float*)d_in[8];
    const float* bv    = (const float*)d_in[9];
    const float* bo    = (const float*)d_in[10];
    const float* fcw   = (const float*)d_in[11];
    const float* fcb   = (const float*)d_in[12];
    float* out = (float*)d_out;
    float* ws  = (float*)d_ws;

    const size_t SZ = (size_t)BATCH * SEQ * EDIM;    // 4,194,304 floats = 16 MiB
    float* h   = ws;                                  // S0: h fp32 (final layer only)
    short* qf  = (short*)(ws + SZ);                   // S1: Q frags (16 MiB exactly)
    short* afo = (short*)(ws + 2 * SZ);               // S2: attn-out frags
    short* afx = (short*)(ws + 3 * SZ);               // S3: x frags (4 MiB used)
    short* wfe = afx + 4 * 1024 * 1024;               // S3 tail: emb weight frags
    short* kf  = (short*)(ws + 4 * SZ);               // S4
    short* vf  = (short*)(ws + 5 * SZ);               // S5
    short* afh = (short*)(ws + 6 * SZ);               // S6: h frags
    short* wf  = (short*)(ws + 7 * SZ);               // S7: 16 x 524288 shorts

    const int M = BATCH * SEQ;                        // 8192
    const dim3 gG(M / 128, EDIM / 64);                // (64, 8)
    const dim3 gQKV(M / 128, 3 * EDIM / 64);          // (64, 24)
    const dim3 gA(BATCH * NH, SEQ / 16);              // (64, 64)

    conv_wall<<<dim3(4, 32, 16), 256, 0, stream>>>(Wq, Wk, Wv, Wo, wf);
    conv_w1<<<dim3(1, 32), 256, 0, stream>>>(emb_w, wfe, 128, EDIM);
    conv_a<<<dim3(1, M / 16), 256, 0, stream>>>(x, afx, 128);
    gemm_af<<<gG, 256, 0, stream>>>(afx, wfe, emb_b, nullptr, afh, 128);

    for (int l = 0; l < NLAYER; ++l) {
        const short* wfl = wf + (size_t)(4 * l) * 524288;
        gemm_qkv<<<gQKV, 256, 0, stream>>>(afh, wfl, bq + l * EDIM, bk + l * EDIM,
                                           bv + l * EDIM, qf, kf, vf);
        attn_mfma<<<gA, 512, 0, stream>>>(qf, kf, vf, afo);
        gemm_af<<<gG, 256, 0, stream>>>(afo, wfl + 3 * 524288, bo + l * EDIM,
                                        (l == NLAYER - 1) ? h : nullptr, afh, EDIM);
    }
    mean_fc<<<8, 256, 0, stream>>>(h, fcw, fcb, out);
}